// Round 11
// baseline (559.757 us; speedup 1.0000x reference)
//
#include <hip/hip_runtime.h>
#include <math.h>

#define NT 65536
#define EE 1048576
#define NB 128
#define KK 410          // kept nodes per graph = ceil(0.8*512)
#define HH 128

typedef short bf16x8 __attribute__((ext_vector_type(8)));
typedef float f32x4 __attribute__((ext_vector_type(4)));

// ---------------- device scratch -------------------------------------------
__device__ unsigned short g_xb[(size_t)NT * 64];
__device__ unsigned short g_hb1[(size_t)NT * HH];
__device__ unsigned short g_hb2[(size_t)NT * HH];
__device__ unsigned short g_wt1[128 * 128];
__device__ unsigned short g_wtc[3 * 128 * 256];
__device__ unsigned short g_csr1u[EE];   // src id per edge, grouped by dst
__device__ unsigned short g_keptu[NT];   // 1 if node kept by SAGPool
__device__ unsigned int g_ebuck[EE];     // packed (dstLocal<<16)|src, bucketed by graph
__device__ int g_bcnt[128];              // zero at load; re-zeroed by k_topk each call
__device__ int g_bcur[128];              // ditto
__device__ float g_trel[NT];
__device__ float g_troot[NT];
__device__ float g_gatef[NT];            // tanh(score) if kept else 0
__device__ float g_kinv[NT];             // 1/max(kept-neighbor count,1)
__device__ float g_xc16[4 * NB * 16 * 128]; // pooled partials [sec][graph][16th][128]
__device__ int g_rows1[NT + 1];

__device__ __forceinline__ unsigned short* ubuf(int id) {
    switch (id) {
        case 0: return g_xb;
        case 1: return g_hb1;
        case 2: return g_hb2;
        case 3: return g_wt1;
        case 4: return g_wtc;
    }
    return g_xb;
}

__device__ __forceinline__ float b2f(unsigned short u) {
    union { unsigned int i; float f; } v;
    v.i = ((unsigned int)u) << 16;
    return v.f;
}
__device__ __forceinline__ unsigned short f2b(float f) {
    unsigned int x = __float_as_uint(f);
    unsigned int r = x + 0x7fffu + ((x >> 16) & 1u);   // round-to-nearest-even
    return (unsigned short)(r >> 16);
}
__device__ __forceinline__ bf16x8 scale8(bf16x8 a, float g) {
    bf16x8 r;
#pragma unroll
    for (int i = 0; i < 8; i++) {
        unsigned short u = (unsigned short)a[i];
        r[i] = (short)f2b(b2f(u) * g);
    }
    return r;
}

// ---------------- prep + bucket histogram (independent halves, no handoff) --
// NOTE (R7 post-mortem): never do grid-wide producer->consumer handoff inside
// one kernel via __threadfence on CDNA4 — per-XCD L2 non-coherence makes each
// block's device-scope fence an L2 writeback (5568 of them = 450us).
__global__ __launch_bounds__(256) void k_prep(const float* __restrict__ x,
                                              const float* __restrict__ W1r,
                                              const float* __restrict__ W1o,
                                              const float* __restrict__ Wcr,
                                              const float* __restrict__ Wco,
                                              const int* __restrict__ dst) {
    if (blockIdx.x < 4544) {
        int tid = blockIdx.x * 256 + threadIdx.x;
        if (tid < 1048576) {
            float4 v = *(const float4*)&x[(size_t)tid * 4];
            unsigned int lo = (unsigned int)f2b(v.x) | ((unsigned int)f2b(v.y) << 16);
            unsigned int hi = (unsigned int)f2b(v.z) | ((unsigned int)f2b(v.w) << 16);
            *(uint2*)&g_xb[(size_t)tid * 4] = make_uint2(lo, hi);
        } else if (tid < 1048576 + 16384) {
            int r = tid - 1048576;
            int k = r & 127, n = r >> 7;
            float v = (k < 64) ? W1r[k * 128 + n] : W1o[(k - 64) * 128 + n];
            g_wt1[n * 128 + k] = f2b(v);
        } else {
            int r = tid - (1048576 + 16384);
            int l = r >> 15;
            int k = r & 255, n = (r >> 8) & 127;
            float v = (k < 128) ? Wcr[l * 16384 + k * 128 + n]
                                : Wco[l * 16384 + (k - 128) * 128 + n];
            g_wtc[l * 32768 + n * 256 + k] = f2b(v);
        }
    } else {
        __shared__ int h[128];
        if (threadIdx.x < 128) h[threadIdx.x] = 0;
        __syncthreads();
        int e0 = ((blockIdx.x - 4544) * 256 + threadIdx.x) * 4;
        int4 d = *(const int4*)&dst[e0];
        atomicAdd(&h[d.x >> 9], 1);
        atomicAdd(&h[d.y >> 9], 1);
        atomicAdd(&h[d.z >> 9], 1);
        atomicAdd(&h[d.w >> 9], 1);
        __syncthreads();
        if (threadIdx.x < 128 && h[threadIdx.x]) atomicAdd(&g_bcnt[threadIdx.x], h[threadIdx.x]);
    }
}

// ---------------- CSR1: scatter into bucket regions (local bucket scan) -----
__global__ __launch_bounds__(256) void k_bscatter(const int* __restrict__ src,
                                                  const int* __restrict__ dst) {
    __shared__ int h[128];
    __shared__ int base[128];
    __shared__ int sc[128];
    __shared__ int vv[128];
    int t = threadIdx.x;
    if (t < 128) { vv[t] = g_bcnt[t]; sc[t] = vv[t]; h[t] = 0; }
    __syncthreads();
    for (int off = 1; off < 128; off <<= 1) {
        int u = (t >= off && t < 128) ? sc[t - off] : 0;
        __syncthreads();
        if (t < 128) sc[t] += u;
        __syncthreads();
    }
    int e0 = (blockIdx.x * 256 + t) * 4;
    int4 s = *(const int4*)&src[e0];
    int4 d = *(const int4*)&dst[e0];
    int b0 = d.x >> 9, b1 = d.y >> 9, b2 = d.z >> 9, b3 = d.w >> 9;
    atomicAdd(&h[b0], 1);
    atomicAdd(&h[b1], 1);
    atomicAdd(&h[b2], 1);
    atomicAdd(&h[b3], 1);
    __syncthreads();
    if (t < 128) {
        int c = h[t];
        base[t] = (sc[t] - vv[t]) + (c ? atomicAdd(&g_bcur[t], c) : 0);
        h[t] = 0;
    }
    __syncthreads();
    int r0 = atomicAdd(&h[b0], 1);
    g_ebuck[base[b0] + r0] = ((unsigned int)(d.x & 511) << 16) | (unsigned int)s.x;
    int r1 = atomicAdd(&h[b1], 1);
    g_ebuck[base[b1] + r1] = ((unsigned int)(d.y & 511) << 16) | (unsigned int)s.y;
    int r2 = atomicAdd(&h[b2], 1);
    g_ebuck[base[b2] + r2] = ((unsigned int)(d.z & 511) << 16) | (unsigned int)s.z;
    int r3 = atomicAdd(&h[b3], 1);
    g_ebuck[base[b3] + r3] = ((unsigned int)(d.w & 511) << 16) | (unsigned int)s.w;
}

// ---------------- CSR1: per-graph local CSR build (local bucket scan) -------
__global__ __launch_bounds__(512) void k_bcsr() {
    __shared__ int hist[512];
    __shared__ int offs[512];
    __shared__ int cur[512];
    __shared__ int sc[128];
    int g = blockIdx.x, t = threadIdx.x;
    if (t < 128) sc[t] = g_bcnt[t];
    hist[t] = 0;
    cur[t] = 0;
    __syncthreads();
    for (int off = 1; off < 128; off <<= 1) {
        int u = (t >= off && t < 128) ? sc[t - off] : 0;
        __syncthreads();
        if (t < 128) sc[t] += u;
        __syncthreads();
    }
    int b0 = sc[g] - g_bcnt[g];          // exclusive prefix
    int b1 = sc[g];
    for (int e = b0 + t; e < b1; e += 512) {
        unsigned int p = g_ebuck[e];
        atomicAdd(&hist[p >> 16], 1);
    }
    __syncthreads();
    int v = hist[t];
    offs[t] = v;
    __syncthreads();
    for (int off = 1; off < 512; off <<= 1) {
        int u = (t >= off) ? offs[t - off] : 0;
        __syncthreads();
        offs[t] += u;
        __syncthreads();
    }
    int excl = offs[t] - v;
    g_rows1[g * 512 + t] = b0 + excl;
    if (t == 511) g_rows1[g * 512 + 512] = b0 + excl + v;
    __syncthreads();
    offs[t] = excl;
    __syncthreads();
    for (int e = b0 + t; e < b1; e += 512) {
        unsigned int p = g_ebuck[e];
        int dl = p >> 16;
        int r = atomicAdd(&cur[dl], 1);
        g_csr1u[b0 + offs[dl] + r] = (unsigned short)(p & 0xFFFFu);
    }
}

// ---------------- edge-split wave-pair fused conv ---------------------------
// R10 post-mortem: gather BW tracks resident waves; 16 rows/wave = 4096 waves
// = 16/CU was the ceiling. Here TWO waves co-own each 16-row group, each
// gathers HALF the edge list (8192 waves = 32/CU, thread-capped), partials
// combine through LDS (bf16), then the pair splits the 8 col-tiles 4/4.
// Block 256 thr = 4 waves = 2 groups = 32 rows; grid NT/32 = 2048.
// KC: 0 denom=deg; 1 denom=kept count + store g_kinv; 2 read g_kinv
template <int KA, int KB, int KC, int GATED, int MASKED, int DOTS, int BGATE>
__global__ __launch_bounds__(256, 8) void k_conv(int hId, int bId, int wId, int wOfs,
                                                 const float* __restrict__ bias, int outId,
                                                 int sec,
                                                 const float* __restrict__ pwr,
                                                 const float* __restrict__ pwt) {
    constexpr int NCHA = KA / 32;          // agg K-chunks (8 bf16 per lane per chunk)
    const int K = KA + KB;
    const unsigned short* h = ubuf(hId);
    const unsigned short* Bp = ubuf(bId);
    const unsigned short* Wt = ubuf(wId) + wOfs;
    unsigned short* out = ubuf(outId);
    __shared__ unsigned short part[2][16][136];   // bf16 half-partials
    __shared__ unsigned short frag[2][16][136];   // bf16 combined A-frags
    __shared__ float s[128];
    __shared__ float sdr[32], sdt[32];
    __shared__ int kcs[32];
    int lane = threadIdx.x & 63;
    int w = threadIdx.x >> 6;              // 0..3
    int g = w >> 1;                        // group 0/1 (16 rows each)
    int h2 = w & 1;                        // half: 0=even wave, 1=odd wave
    int n16 = lane & 15, quad = lane >> 4;
    int rowbase = blockIdx.x * 32;
    int rowg = rowbase + g * 16;
    int node = rowg + n16;                 // this lane's row (A m-index)
    if (threadIdx.x < 128) s[threadIdx.x] = 0.f;
    if (threadIdx.x < 32) { sdr[threadIdx.x] = 0.f; sdt[threadIdx.x] = 0.f; }

    // ---------- gather-aggregate HALF the edge list into registers ----------
    int r0 = g_rows1[node], r1 = g_rows1[node + 1];
    int mid = (r0 + r1) >> 1;
    int ea = h2 ? mid : r0;
    int eb = h2 ? r1 : mid;
    float aggacc[NCHA][8];
#pragma unroll
    for (int ch = 0; ch < NCHA; ch++)
#pragma unroll
        for (int j = 0; j < 8; j++) aggacc[ch][j] = 0.f;
    int kc = 0;
    const unsigned short* hq = h + quad * 8;
#define ACC8(arow, v, gf)                                        \
    arow[0] += gf * b2f((unsigned short)(v.x & 0xffff));         \
    arow[1] += gf * b2f((unsigned short)(v.x >> 16));            \
    arow[2] += gf * b2f((unsigned short)(v.y & 0xffff));         \
    arow[3] += gf * b2f((unsigned short)(v.y >> 16));            \
    arow[4] += gf * b2f((unsigned short)(v.z & 0xffff));         \
    arow[5] += gf * b2f((unsigned short)(v.z >> 16));            \
    arow[6] += gf * b2f((unsigned short)(v.w & 0xffff));         \
    arow[7] += gf * b2f((unsigned short)(v.w >> 16));
    int e = ea;
    for (; e + 2 <= eb; e += 2) {
        int i0 = g_csr1u[e], i1 = g_csr1u[e + 1];
        uint4 v0[NCHA], v1[NCHA];
#pragma unroll
        for (int ch = 0; ch < NCHA; ch++)
            v0[ch] = *(const uint4*)&hq[(size_t)i0 * KA + ch * 32];
#pragma unroll
        for (int ch = 0; ch < NCHA; ch++)
            v1[ch] = *(const uint4*)&hq[(size_t)i1 * KA + ch * 32];
        float gf0 = GATED ? g_gatef[i0] : 1.0f;
        float gf1 = GATED ? g_gatef[i1] : 1.0f;
        if (KC == 1) kc += (int)g_keptu[i0] + (int)g_keptu[i1];
#pragma unroll
        for (int ch = 0; ch < NCHA; ch++) { ACC8(aggacc[ch], v0[ch], gf0) }
#pragma unroll
        for (int ch = 0; ch < NCHA; ch++) { ACC8(aggacc[ch], v1[ch], gf1) }
    }
    if (e < eb) {
        int i0 = g_csr1u[e];
        uint4 v0[NCHA];
#pragma unroll
        for (int ch = 0; ch < NCHA; ch++)
            v0[ch] = *(const uint4*)&hq[(size_t)i0 * KA + ch * 32];
        float gf0 = GATED ? g_gatef[i0] : 1.0f;
        if (KC == 1) kc += (int)g_keptu[i0];
#pragma unroll
        for (int ch = 0; ch < NCHA; ch++) { ACC8(aggacc[ch], v0[ch], gf0) }
    }
#undef ACC8

    // even wave: store bf16 half-partials (+ kept count) to LDS
    if (h2 == 0) {
#pragma unroll
        for (int ch = 0; ch < NCHA; ch++) {
            bf16x8 pk;
#pragma unroll
            for (int j = 0; j < 8; j++) pk[j] = (short)f2b(aggacc[ch][j]);
            *(bf16x8*)&part[g][n16][ch * 32 + quad * 8] = pk;
        }
        if (KC == 1 && quad == 0) kcs[g * 16 + n16] = kc;
    }
    __syncthreads();

    // odd wave: combine, normalize, pack combined A-frags to LDS
    if (h2 == 1) {
#pragma unroll
        for (int ch = 0; ch < NCHA; ch++) {
            bf16x8 pv = *(const bf16x8*)&part[g][n16][ch * 32 + quad * 8];
#pragma unroll
            for (int j = 0; j < 8; j++) aggacc[ch][j] += b2f((unsigned short)pv[j]);
        }
        float inv;
        if (KC == 0) {
            int c = r1 - r0;
            inv = 1.0f / (float)(c > 0 ? c : 1);
        } else if (KC == 1) {
            kc += kcs[g * 16 + n16];
            inv = 1.0f / (float)(kc > 0 ? kc : 1);
            if (quad == 0) g_kinv[node] = inv;
        } else {
            inv = g_kinv[node];
        }
#pragma unroll
        for (int ch = 0; ch < NCHA; ch++) {
            bf16x8 fk;
#pragma unroll
            for (int j = 0; j < 8; j++) fk[j] = (short)f2b(aggacc[ch][j] * inv);
            *(bf16x8*)&frag[g][n16][ch * 32 + quad * 8] = fk;
        }
    }
    __syncthreads();

    // ---------- MFMA: pair splits 8 col-tiles 4/4 over full K ----------
    float ga = BGATE ? g_gatef[node] : 1.0f;
    f32x4 acc[4];
#pragma unroll
    for (int c4 = 0; c4 < 4; c4++)
#pragma unroll
        for (int i = 0; i < 4; i++) acc[c4][i] = 0.f;
#pragma unroll
    for (int ks = 0; ks < K / 32; ks++) {
        bf16x8 a;
        if (ks < NCHA) {
            a = *(const bf16x8*)&frag[g][n16][ks * 32 + quad * 8];
        } else {
            int kk = (ks - NCHA) * 32;
            a = *(const bf16x8*)&Bp[(size_t)node * KB + kk + quad * 8];
            if (BGATE) a = scale8(a, ga);
        }
#pragma unroll
        for (int c4 = 0; c4 < 4; c4++) {
            int ct = h2 * 4 + c4;
            bf16x8 b = *(const bf16x8*)&Wt[(size_t)(ct * 16 + n16) * K + ks * 32 + quad * 8];
            acc[c4] = __builtin_amdgcn_mfma_f32_16x16x32_bf16(a, b, acc[c4], 0, 0, 0);
        }
    }

    // ---------- epilogue (C/D: col=ct*16+n16, row=quad*4+i) ----------
    {
        float m[4];
#pragma unroll
        for (int i = 0; i < 4; i++) {
            int r = rowg + quad * 4 + i;
            m[i] = (!MASKED || g_keptu[r]) ? 1.0f : 0.0f;
        }
#pragma unroll
        for (int c4 = 0; c4 < 4; c4++) {
            int c = (h2 * 4 + c4) * 16 + n16;
            float bv = bias[c];
#pragma unroll
            for (int i = 0; i < 4; i++) {
                int r = rowg + quad * 4 + i;
                float v = fmaxf(acc[c4][i] + bv, 0.f) * m[i];
                acc[c4][i] = v;
                out[(size_t)r * 128 + c] = f2b(v);
            }
        }
    }

    // pool partials: column sums over this block's 32 rows
#pragma unroll
    for (int c4 = 0; c4 < 4; c4++) {
        float p = acc[c4][0] + acc[c4][1] + acc[c4][2] + acc[c4][3];
        p += __shfl_xor(p, 16);
        p += __shfl_xor(p, 32);
        if (quad == 0) atomicAdd(&s[(h2 * 4 + c4) * 16 + n16], p);
    }

    // DOTS partials (conv2): this wave's 4 col-tiles contribute to row dots
    if (DOTS) {
        float pr[4], pt[4];
#pragma unroll
        for (int c4 = 0; c4 < 4; c4++) {
            pr[c4] = pwr[(h2 * 4 + c4) * 16 + n16];
            pt[c4] = pwt[(h2 * 4 + c4) * 16 + n16];
        }
#pragma unroll
        for (int i = 0; i < 4; i++) {
            float dr = 0.f, dt = 0.f;
#pragma unroll
            for (int c4 = 0; c4 < 4; c4++) {
                dr += acc[c4][i] * pr[c4];
                dt += acc[c4][i] * pt[c4];
            }
            dr += __shfl_xor(dr, 1); dt += __shfl_xor(dt, 1);
            dr += __shfl_xor(dr, 2); dt += __shfl_xor(dt, 2);
            dr += __shfl_xor(dr, 4); dt += __shfl_xor(dt, 4);
            dr += __shfl_xor(dr, 8); dt += __shfl_xor(dt, 8);
            if (n16 == 0) {
                atomicAdd(&sdr[g * 16 + quad * 4 + i], dr);
                atomicAdd(&sdt[g * 16 + quad * 4 + i], dt);
            }
        }
    }
    __syncthreads();
    if (threadIdx.x < 128) {
        int gr = blockIdx.x >> 4, e16 = blockIdx.x & 15;
        g_xc16[((sec * NB + gr) * 16 + e16) * 128 + threadIdx.x] = s[threadIdx.x];
    }
    if (DOTS && threadIdx.x < 32) {
        g_trel[rowbase + threadIdx.x] = sdr[threadIdx.x];
        g_troot[rowbase + threadIdx.x] = sdt[threadIdx.x];
    }
}

// ---------------- SAGPool: fused score + per-graph bitonic top-410 ----------
// Also re-zeros g_bcnt/g_bcur for the next call (their last consumer, k_bcsr,
// ran earlier in this call; load-time zero covers call 1).
__global__ __launch_bounds__(256) void k_topk(const float* __restrict__ pb) {
    __shared__ float sv[512];
    __shared__ int si[512];
    int g = blockIdx.x, t = threadIdx.x;
    if (t == 0) { g_bcnt[g] = 0; g_bcur[g] = 0; }
    float pbv = pb[0];
    for (int l = t; l < 512; l += 256) {
        int node = g * 512 + l;
        int r0 = g_rows1[node], r1 = g_rows1[node + 1];
        float s = 0.f;
        int e = r0;
        for (; e + 4 <= r1; e += 4) {
            float s0 = g_trel[g_csr1u[e]];
            float s1 = g_trel[g_csr1u[e + 1]];
            float s2 = g_trel[g_csr1u[e + 2]];
            float s3 = g_trel[g_csr1u[e + 3]];
            s += (s0 + s1) + (s2 + s3);
        }
        for (; e < r1; e++) s += g_trel[g_csr1u[e]];
        sv[l] = s + g_troot[node] + pbv;
        si[l] = l;
    }
    __syncthreads();
    for (int k = 2; k <= 512; k <<= 1) {
        for (int j = k >> 1; j > 0; j >>= 1) {
            for (int i = t; i < 512; i += 256) {
                int p = i ^ j;
                if (p > i) {
                    float va = sv[i], vb = sv[p];
                    int ia = si[i], ib = si[p];
                    bool aFirst = (va > vb) || (va == vb && ia < ib);
                    bool up = ((i & k) == 0);
                    if (up != aFirst) { sv[i] = vb; sv[p] = va; si[i] = ib; si[p] = ia; }
                }
            }
            __syncthreads();
        }
    }
    for (int r = t; r < 512; r += 256) {
        int old = g * 512 + si[r];
        if (r < KK) {
            g_gatef[old] = tanhf(sv[r]);
            g_keptu[old] = 1;
        } else {
            g_gatef[old] = 0.f;
            g_keptu[old] = 0;
        }
    }
}

// ---------------- MLP head + log_softmax ------------------------------------
__global__ __launch_bounds__(128) void k_head(const float* __restrict__ W1, const float* __restrict__ b1,
                                              const float* __restrict__ W2, const float* __restrict__ b2,
                                              float* __restrict__ out) {
    __shared__ float xr[512];
    __shared__ float r0[128], r1[128];
    int g = blockIdx.x, t = threadIdx.x;
    for (int i = t; i < 512; i += 128) {
        int sec = i >> 7, c = i & 127;
        const float* p = &g_xc16[((sec * NB + g) * 16) * 128 + c];
        float v = 0.f;
#pragma unroll
        for (int q = 0; q < 16; q++) v += p[q * 128];
        float inv = (sec < 2) ? (1.0f / 512.0f) : (1.0f / 410.0f);
        xr[i] = v * inv;
    }
    __syncthreads();
    float acc = b1[t];
    for (int k = 0; k < 512; k++) acc += xr[k] * W1[k * 128 + t];
    acc = fmaxf(acc, 0.f);
    r0[t] = acc * W2[t * 2 + 0];
    r1[t] = acc * W2[t * 2 + 1];
    __syncthreads();
    for (int off = 64; off > 0; off >>= 1) {
        if (t < off) { r0[t] += r0[t + off]; r1[t] += r1[t + off]; }
        __syncthreads();
    }
    if (t == 0) {
        float z0 = r0[0] + b2[0], z1 = r1[0] + b2[1];
        float m = fmaxf(z0, z1);
        float l = m + logf(expf(z0 - m) + expf(z1 - m));
        out[g * 2 + 0] = z0 - l;
        out[g * 2 + 1] = z1 - l;
    }
}

// ---------------- launch -----------------------------------------------------
extern "C" void kernel_launch(void* const* d_in, const int* in_sizes, int n_in,
                              void* d_out, int out_size, void* d_ws, size_t ws_size,
                              hipStream_t stream) {
    const float* x = (const float*)d_in[0];
    const int* ei = (const int*)d_in[1];
    const int* src = ei;
    const int* dst = ei + EE;
    const float* W1r = (const float*)d_in[3];
    const float* W1o = (const float*)d_in[4];
    const float* b1 = (const float*)d_in[5];
    const float* Wcr = (const float*)d_in[6];
    const float* Wco = (const float*)d_in[7];
    const float* bc = (const float*)d_in[8];
    const float* pwr = (const float*)d_in[9];
    const float* pwt = (const float*)d_in[10];
    const float* pb = (const float*)d_in[11];
    const float* l1W = (const float*)d_in[12];
    const float* l1b = (const float*)d_in[13];
    const float* l2W = (const float*)d_in[14];
    const float* l2b = (const float*)d_in[15];
    float* out = (float*)d_out;

    // ---- prep (x/weights -> bf16) + bucket histogram (independent halves) ----
    k_prep<<<5568, 256, 0, stream>>>(x, W1r, W1o, Wcr, Wco, dst);

    // ---- CSR1: scatter (local bucket scan), per-graph CSR (local scan) ----
    k_bscatter<<<1024, 256, 0, stream>>>(src, dst);
    k_bcsr<<<128, 512, 0, stream>>>();

    // ---- conv1: hb1 = relu([agg64(xb)|xb]@wt1+b1); pool sec0 ----
    k_conv<64, 64, 0, 0, 0, 0, 0><<<2048, 256, 0, stream>>>(0, 0, 3, 0, b1, 1, 0, pwr, pwt);

    // ---- conv2 -> hb2; pool sec1; score dots fused ----
    k_conv<128, 128, 0, 0, 0, 1, 0><<<2048, 256, 0, stream>>>(1, 1, 4, 0, bc, 2, 1, pwr, pwt);

    // ---- SAGPool: fused score + top-410 -> gatef/keptu (+ counter re-zero) ----
    k_topk<<<NB, 256, 0, stream>>>(pb);

    // ---- conv3: gated agg(hb2), kept-denominator, BGATE root, masked -> hb1; sec2 ----
    k_conv<128, 128, 1, 1, 1, 0, 1><<<2048, 256, 0, stream>>>(2, 2, 4, 32768, bc + 128, 1, 2, pwr, pwt);

    // ---- conv4: agg(hb1), kinv reuse, masked -> hb2; sec3 ----
    k_conv<128, 128, 2, 0, 1, 0, 0><<<2048, 256, 0, stream>>>(1, 1, 4, 65536, bc + 256, 2, 3, pwr, pwt);

    // ---- head ----
    k_head<<<NB, 128, 0, stream>>>(l1W, l1b, l2W, l2b, out);
}

// Round 12
// 527.162 us; speedup vs baseline: 1.0618x; 1.0618x over previous
//
#include <hip/hip_runtime.h>
#include <math.h>

#define NT 65536
#define EE 1048576
#define NB 128
#define KK 410          // kept nodes per graph = ceil(0.8*512)
#define HH 128

typedef short bf16x8 __attribute__((ext_vector_type(8)));
typedef float f32x4 __attribute__((ext_vector_type(4)));

// ---------------- device scratch -------------------------------------------
__device__ unsigned short g_xb[(size_t)NT * 64];
__device__ unsigned short g_hb1[(size_t)NT * HH];
__device__ unsigned short g_hb2[(size_t)NT * HH];
__device__ unsigned short g_wt1[128 * 128];
__device__ unsigned short g_wtc[3 * 128 * 256];
__device__ unsigned short g_csr1u[EE];   // src id per edge, grouped by dst
__device__ unsigned short g_keptu[NT];   // 1 if node kept by SAGPool
__device__ unsigned int g_ebuck[EE];     // packed (dstLocal<<16)|src, bucketed by graph
__device__ int g_bcnt[128];              // zero at load; re-zeroed by k_topk each call
__device__ int g_bcur[128];              // ditto
__device__ float g_trel[NT];
__device__ float g_troot[NT];
__device__ float g_gatef[NT];            // tanh(score) if kept else 0
__device__ float g_kinv[NT];             // 1/max(kept-neighbor count,1)
__device__ float g_xc16[4 * NB * 16 * 128]; // pooled partials [sec][graph][slot][128]
__device__ int g_rows1[NT + 1];

__device__ __forceinline__ float b2f(unsigned short u) {
    union { unsigned int i; float f; } v;
    v.i = ((unsigned int)u) << 16;
    return v.f;
}
__device__ __forceinline__ unsigned short f2b(float f) {
    unsigned int x = __float_as_uint(f);
    unsigned int r = x + 0x7fffu + ((x >> 16) & 1u);   // round-to-nearest-even
    return (unsigned short)(r >> 16);
}
__device__ __forceinline__ bf16x8 scale8(bf16x8 a, float g) {
    bf16x8 r;
#pragma unroll
    for (int i = 0; i < 8; i++) {
        unsigned short u = (unsigned short)a[i];
        r[i] = (short)f2b(b2f(u) * g);
    }
    return r;
}

// ---------------- prep + bucket histogram (independent halves, no handoff) --
// NOTE (R7 post-mortem): never do grid-wide producer->consumer handoff inside
// one kernel via __threadfence on CDNA4 — per-XCD L2 non-coherence makes each
// block's device-scope fence an L2 writeback (5568 of them = 450us).
__global__ __launch_bounds__(256) void k_prep(const float* __restrict__ x,
                                              const float* __restrict__ W1r,
                                              const float* __restrict__ W1o,
                                              const float* __restrict__ Wcr,
                                              const float* __restrict__ Wco,
                                              const int* __restrict__ dst) {
    if (blockIdx.x < 4544) {
        int tid = blockIdx.x * 256 + threadIdx.x;
        if (tid < 1048576) {
            float4 v = *(const float4*)&x[(size_t)tid * 4];
            unsigned int lo = (unsigned int)f2b(v.x) | ((unsigned int)f2b(v.y) << 16);
            unsigned int hi = (unsigned int)f2b(v.z) | ((unsigned int)f2b(v.w) << 16);
            *(uint2*)&g_xb[(size_t)tid * 4] = make_uint2(lo, hi);
        } else if (tid < 1048576 + 16384) {
            int r = tid - 1048576;
            int k = r & 127, n = r >> 7;
            float v = (k < 64) ? W1r[k * 128 + n] : W1o[(k - 64) * 128 + n];
            g_wt1[n * 128 + k] = f2b(v);
        } else {
            int r = tid - (1048576 + 16384);
            int l = r >> 15;
            int k = r & 255, n = (r >> 8) & 127;
            float v = (k < 128) ? Wcr[l * 16384 + k * 128 + n]
                                : Wco[l * 16384 + (k - 128) * 128 + n];
            g_wtc[l * 32768 + n * 256 + k] = f2b(v);
        }
    } else {
        __shared__ int h[128];
        if (threadIdx.x < 128) h[threadIdx.x] = 0;
        __syncthreads();
        int e0 = ((blockIdx.x - 4544) * 256 + threadIdx.x) * 4;
        int4 d = *(const int4*)&dst[e0];
        atomicAdd(&h[d.x >> 9], 1);
        atomicAdd(&h[d.y >> 9], 1);
        atomicAdd(&h[d.z >> 9], 1);
        atomicAdd(&h[d.w >> 9], 1);
        __syncthreads();
        if (threadIdx.x < 128 && h[threadIdx.x]) atomicAdd(&g_bcnt[threadIdx.x], h[threadIdx.x]);
    }
}

// ---------------- CSR1: scatter into bucket regions (local bucket scan) -----
__global__ __launch_bounds__(256) void k_bscatter(const int* __restrict__ src,
                                                  const int* __restrict__ dst) {
    __shared__ int h[128];
    __shared__ int base[128];
    __shared__ int sc[128];
    __shared__ int vv[128];
    int t = threadIdx.x;
    if (t < 128) { vv[t] = g_bcnt[t]; sc[t] = vv[t]; h[t] = 0; }
    __syncthreads();
    for (int off = 1; off < 128; off <<= 1) {
        int u = (t >= off && t < 128) ? sc[t - off] : 0;
        __syncthreads();
        if (t < 128) sc[t] += u;
        __syncthreads();
    }
    int e0 = (blockIdx.x * 256 + t) * 4;
    int4 s = *(const int4*)&src[e0];
    int4 d = *(const int4*)&dst[e0];
    int b0 = d.x >> 9, b1 = d.y >> 9, b2 = d.z >> 9, b3 = d.w >> 9;
    atomicAdd(&h[b0], 1);
    atomicAdd(&h[b1], 1);
    atomicAdd(&h[b2], 1);
    atomicAdd(&h[b3], 1);
    __syncthreads();
    if (t < 128) {
        int c = h[t];
        base[t] = (sc[t] - vv[t]) + (c ? atomicAdd(&g_bcur[t], c) : 0);
        h[t] = 0;
    }
    __syncthreads();
    int r0 = atomicAdd(&h[b0], 1);
    g_ebuck[base[b0] + r0] = ((unsigned int)(d.x & 511) << 16) | (unsigned int)s.x;
    int r1 = atomicAdd(&h[b1], 1);
    g_ebuck[base[b1] + r1] = ((unsigned int)(d.y & 511) << 16) | (unsigned int)s.y;
    int r2 = atomicAdd(&h[b2], 1);
    g_ebuck[base[b2] + r2] = ((unsigned int)(d.z & 511) << 16) | (unsigned int)s.z;
    int r3 = atomicAdd(&h[b3], 1);
    g_ebuck[base[b3] + r3] = ((unsigned int)(d.w & 511) << 16) | (unsigned int)s.w;
}

// ---------------- CSR1: per-graph local CSR build (local bucket scan) -------
__global__ __launch_bounds__(512) void k_bcsr() {
    __shared__ int hist[512];
    __shared__ int offs[512];
    __shared__ int cur[512];
    __shared__ int sc[128];
    int g = blockIdx.x, t = threadIdx.x;
    if (t < 128) sc[t] = g_bcnt[t];
    hist[t] = 0;
    cur[t] = 0;
    __syncthreads();
    for (int off = 1; off < 128; off <<= 1) {
        int u = (t >= off && t < 128) ? sc[t - off] : 0;
        __syncthreads();
        if (t < 128) sc[t] += u;
        __syncthreads();
    }
    int b0 = sc[g] - g_bcnt[g];          // exclusive prefix
    int b1 = sc[g];
    for (int e = b0 + t; e < b1; e += 512) {
        unsigned int p = g_ebuck[e];
        atomicAdd(&hist[p >> 16], 1);
    }
    __syncthreads();
    int v = hist[t];
    offs[t] = v;
    __syncthreads();
    for (int off = 1; off < 512; off <<= 1) {
        int u = (t >= off) ? offs[t - off] : 0;
        __syncthreads();
        offs[t] += u;
        __syncthreads();
    }
    int excl = offs[t] - v;
    g_rows1[g * 512 + t] = b0 + excl;
    if (t == 511) g_rows1[g * 512 + 512] = b0 + excl + v;
    __syncthreads();
    offs[t] = excl;
    __syncthreads();
    for (int e = b0 + t; e < b1; e += 512) {
        unsigned int p = g_ebuck[e];
        int dl = p >> 16;
        int r = atomicAdd(&cur[dl], 1);
        g_csr1u[b0 + offs[dl] + r] = (unsigned short)(p & 0xFFFFu);
    }
}

// ---------------- conv1: register-fragment (R10 style, K=64|64) -------------
__global__ __launch_bounds__(256, 4) void k_conv1(const float* __restrict__ bias) {
    const unsigned short* h = g_xb;
    const unsigned short* Wt = g_wt1;
    unsigned short* out = g_hb1;
    __shared__ float s[128];
    int lane = threadIdx.x & 63;
    int w = threadIdx.x >> 6;
    int n16 = lane & 15, quad = lane >> 4;
    int rowbase = blockIdx.x * 64;
    int rowg = rowbase + w * 16;
    int node = rowg + n16;
    if (threadIdx.x < 128) s[threadIdx.x] = 0.f;
    int r0 = g_rows1[node], r1 = g_rows1[node + 1];
    float aggacc[2][8];
#pragma unroll
    for (int ch = 0; ch < 2; ch++)
#pragma unroll
        for (int j = 0; j < 8; j++) aggacc[ch][j] = 0.f;
    const unsigned short* hq = h + quad * 8;
#define ACC8(arow, v)                                            \
    arow[0] += b2f((unsigned short)(v.x & 0xffff));              \
    arow[1] += b2f((unsigned short)(v.x >> 16));                 \
    arow[2] += b2f((unsigned short)(v.y & 0xffff));              \
    arow[3] += b2f((unsigned short)(v.y >> 16));                 \
    arow[4] += b2f((unsigned short)(v.z & 0xffff));              \
    arow[5] += b2f((unsigned short)(v.z >> 16));                 \
    arow[6] += b2f((unsigned short)(v.w & 0xffff));              \
    arow[7] += b2f((unsigned short)(v.w >> 16));
    int e = r0;
    for (; e + 2 <= r1; e += 2) {
        int i0 = g_csr1u[e], i1 = g_csr1u[e + 1];
        uint4 v00 = *(const uint4*)&hq[(size_t)i0 * 64];
        uint4 v01 = *(const uint4*)&hq[(size_t)i0 * 64 + 32];
        uint4 v10 = *(const uint4*)&hq[(size_t)i1 * 64];
        uint4 v11 = *(const uint4*)&hq[(size_t)i1 * 64 + 32];
        ACC8(aggacc[0], v00) ACC8(aggacc[1], v01)
        ACC8(aggacc[0], v10) ACC8(aggacc[1], v11)
    }
    if (e < r1) {
        int i0 = g_csr1u[e];
        uint4 v00 = *(const uint4*)&hq[(size_t)i0 * 64];
        uint4 v01 = *(const uint4*)&hq[(size_t)i0 * 64 + 32];
        ACC8(aggacc[0], v00) ACC8(aggacc[1], v01)
    }
#undef ACC8
    int c = r1 - r0;
    float inv = 1.0f / (float)(c > 0 ? c : 1);
    bf16x8 afrag[2];
#pragma unroll
    for (int ch = 0; ch < 2; ch++)
#pragma unroll
        for (int j = 0; j < 8; j++) afrag[ch][j] = (short)f2b(aggacc[ch][j] * inv);

    f32x4 acc[8];
#pragma unroll
    for (int ct = 0; ct < 8; ct++)
#pragma unroll
        for (int i = 0; i < 4; i++) acc[ct][i] = 0.f;
#pragma unroll
    for (int ks = 0; ks < 4; ks++) {
        bf16x8 a;
        if (ks < 2) a = afrag[ks];
        else a = *(const bf16x8*)&g_xb[(size_t)node * 64 + (ks - 2) * 32 + quad * 8];
#pragma unroll
        for (int ct = 0; ct < 8; ct++) {
            bf16x8 b = *(const bf16x8*)&Wt[(size_t)(ct * 16 + n16) * 128 + ks * 32 + quad * 8];
            acc[ct] = __builtin_amdgcn_mfma_f32_16x16x32_bf16(a, b, acc[ct], 0, 0, 0);
        }
    }
#pragma unroll
    for (int ct = 0; ct < 8; ct++) {
        int cc = ct * 16 + n16;
        float bv = bias[cc];
#pragma unroll
        for (int i = 0; i < 4; i++) {
            int r = rowg + quad * 4 + i;
            float v = fmaxf(acc[ct][i] + bv, 0.f);
            acc[ct][i] = v;
            out[(size_t)r * 128 + cc] = f2b(v);
        }
    }
    __syncthreads();
#pragma unroll
    for (int ct = 0; ct < 8; ct++) {
        float p = acc[ct][0] + acc[ct][1] + acc[ct][2] + acc[ct][3];
        p += __shfl_xor(p, 16);
        p += __shfl_xor(p, 32);
        if (quad == 0) atomicAdd(&s[ct * 16 + n16], p);
    }
    __syncthreads();
    if (threadIdx.x < 128) {
        int gr = blockIdx.x >> 3, e8 = blockIdx.x & 7;   // 8 partial slots (sec 0)
        g_xc16[((0 * NB + gr) * 16 + e8) * 128 + threadIdx.x] = s[threadIdx.x];
    }
}

// ---------------- column-split wave-pair fused conv (K=128|128) -------------
// R11 post-mortem: edge-split hit 64-VGPR cap and spilled (WRITE 188MB).
// Column-half split keeps 32 waves/CU but halves register demand: each wave
// of a pair gathers ALL edges of its 16 rows but only a 64-col (=128B,
// line-aligned) half — aggacc[2][8]+v[2]x2 ~ 50 VGPR. Halves are disjoint
// cols so no combine; pair exchanges normalized bf16 A-frags via LDS, then
// splits the 8 col-tiles 4/4. Grid NT/32 = 2048 blocks = 32 waves/CU.
// KC: 0 denom=deg; 1 denom=kept count + store g_kinv; 2 read g_kinv
template <int KC, int GATED, int MASKED, int DOTS, int BGATE>
__global__ __launch_bounds__(256, 8) void k_conv(int hSel, int bSel, int wOfs,
                                                 const float* __restrict__ bias, int outSel,
                                                 int sec,
                                                 const float* __restrict__ pwr,
                                                 const float* __restrict__ pwt) {
    const unsigned short* h = hSel == 1 ? g_hb1 : g_hb2;
    const unsigned short* Bp = bSel == 1 ? g_hb1 : g_hb2;
    const unsigned short* Wt = g_wtc + wOfs;
    unsigned short* out = outSel == 1 ? g_hb1 : g_hb2;
    __shared__ unsigned short frag[2][16][136];   // combined bf16 A-frags (+pad)
    __shared__ float s[128];
    __shared__ float sdr[32], sdt[32];
    int lane = threadIdx.x & 63;
    int w = threadIdx.x >> 6;              // 0..3
    int g = w >> 1;                        // group 0/1 (16 rows each)
    int h2 = w & 1;                        // column half 0/1
    int n16 = lane & 15, quad = lane >> 4;
    int rowbase = blockIdx.x * 32;
    int rowg = rowbase + g * 16;
    int node = rowg + n16;
    if (threadIdx.x < 128) s[threadIdx.x] = 0.f;
    if (threadIdx.x < 32) { sdr[threadIdx.x] = 0.f; sdt[threadIdx.x] = 0.f; }

    // ---------- gather ALL edges, this wave's 64-col half ----------
    int r0 = g_rows1[node], r1 = g_rows1[node + 1];
    float aggacc[2][8];
#pragma unroll
    for (int ch = 0; ch < 2; ch++)
#pragma unroll
        for (int j = 0; j < 8; j++) aggacc[ch][j] = 0.f;
    int kc = 0;
    const unsigned short* hq = h + h2 * 64 + quad * 8;
#define ACC8(arow, v, gf)                                        \
    arow[0] += gf * b2f((unsigned short)(v.x & 0xffff));         \
    arow[1] += gf * b2f((unsigned short)(v.x >> 16));            \
    arow[2] += gf * b2f((unsigned short)(v.y & 0xffff));         \
    arow[3] += gf * b2f((unsigned short)(v.y >> 16));            \
    arow[4] += gf * b2f((unsigned short)(v.z & 0xffff));         \
    arow[5] += gf * b2f((unsigned short)(v.z >> 16));            \
    arow[6] += gf * b2f((unsigned short)(v.w & 0xffff));         \
    arow[7] += gf * b2f((unsigned short)(v.w >> 16));
    int e = r0;
    for (; e + 2 <= r1; e += 2) {
        int i0 = g_csr1u[e], i1 = g_csr1u[e + 1];
        uint4 v00 = *(const uint4*)&hq[(size_t)i0 * 128];
        uint4 v01 = *(const uint4*)&hq[(size_t)i0 * 128 + 32];
        uint4 v10 = *(const uint4*)&hq[(size_t)i1 * 128];
        uint4 v11 = *(const uint4*)&hq[(size_t)i1 * 128 + 32];
        float gf0 = GATED ? g_gatef[i0] : 1.0f;
        float gf1 = GATED ? g_gatef[i1] : 1.0f;
        if (KC == 1) kc += (int)g_keptu[i0] + (int)g_keptu[i1];
        ACC8(aggacc[0], v00, gf0) ACC8(aggacc[1], v01, gf0)
        ACC8(aggacc[0], v10, gf1) ACC8(aggacc[1], v11, gf1)
    }
    if (e < r1) {
        int i0 = g_csr1u[e];
        uint4 v00 = *(const uint4*)&hq[(size_t)i0 * 128];
        uint4 v01 = *(const uint4*)&hq[(size_t)i0 * 128 + 32];
        float gf0 = GATED ? g_gatef[i0] : 1.0f;
        if (KC == 1) kc += (int)g_keptu[i0];
        ACC8(aggacc[0], v00, gf0) ACC8(aggacc[1], v01, gf0)
    }
#undef ACC8
    float inv;
    if (KC == 0) {
        int c = r1 - r0;
        inv = 1.0f / (float)(c > 0 ? c : 1);
    } else if (KC == 1) {
        inv = 1.0f / (float)(kc > 0 ? kc : 1);
        if (h2 == 0 && quad == 0) g_kinv[node] = inv;
    } else {
        inv = g_kinv[node];
    }
    // write normalized bf16 frags for this half into LDS
#pragma unroll
    for (int ch = 0; ch < 2; ch++) {
        bf16x8 fk;
#pragma unroll
        for (int j = 0; j < 8; j++) fk[j] = (short)f2b(aggacc[ch][j] * inv);
        *(bf16x8*)&frag[g][n16][h2 * 64 + ch * 32 + quad * 8] = fk;
    }
    __syncthreads();

    // ---------- MFMA: pair splits 8 col-tiles 4/4 over full K=256 ----------
    float ga = BGATE ? g_gatef[node] : 1.0f;
    f32x4 acc[4];
#pragma unroll
    for (int c4 = 0; c4 < 4; c4++)
#pragma unroll
        for (int i = 0; i < 4; i++) acc[c4][i] = 0.f;
#pragma unroll
    for (int ks = 0; ks < 8; ks++) {
        bf16x8 a;
        if (ks < 4) {
            a = *(const bf16x8*)&frag[g][n16][ks * 32 + quad * 8];
        } else {
            a = *(const bf16x8*)&Bp[(size_t)node * 128 + (ks - 4) * 32 + quad * 8];
            if (BGATE) a = scale8(a, ga);
        }
#pragma unroll
        for (int c4 = 0; c4 < 4; c4++) {
            int ct = h2 * 4 + c4;
            bf16x8 b = *(const bf16x8*)&Wt[(size_t)(ct * 16 + n16) * 256 + ks * 32 + quad * 8];
            acc[c4] = __builtin_amdgcn_mfma_f32_16x16x32_bf16(a, b, acc[c4], 0, 0, 0);
        }
    }

    // ---------- epilogue (C/D: col=ct*16+n16, row=quad*4+i) ----------
    {
        float m[4];
#pragma unroll
        for (int i = 0; i < 4; i++) {
            int r = rowg + quad * 4 + i;
            m[i] = (!MASKED || g_keptu[r]) ? 1.0f : 0.0f;
        }
#pragma unroll
        for (int c4 = 0; c4 < 4; c4++) {
            int c = (h2 * 4 + c4) * 16 + n16;
            float bv = bias[c];
#pragma unroll
            for (int i = 0; i < 4; i++) {
                int r = rowg + quad * 4 + i;
                float v = fmaxf(acc[c4][i] + bv, 0.f) * m[i];
                acc[c4][i] = v;
                out[(size_t)r * 128 + c] = f2b(v);
            }
        }
    }

    // pool partials: column sums over this block's 32 rows
#pragma unroll
    for (int c4 = 0; c4 < 4; c4++) {
        float p = acc[c4][0] + acc[c4][1] + acc[c4][2] + acc[c4][3];
        p += __shfl_xor(p, 16);
        p += __shfl_xor(p, 32);
        if (quad == 0) atomicAdd(&s[(h2 * 4 + c4) * 16 + n16], p);
    }

    // DOTS partials (conv2): this wave's 4 col-tiles contribute to row dots
    if (DOTS) {
        float pr[4], pt[4];
#pragma unroll
        for (int c4 = 0; c4 < 4; c4++) {
            pr[c4] = pwr[(h2 * 4 + c4) * 16 + n16];
            pt[c4] = pwt[(h2 * 4 + c4) * 16 + n16];
        }
#pragma unroll
        for (int i = 0; i < 4; i++) {
            float dr = 0.f, dt = 0.f;
#pragma unroll
            for (int c4 = 0; c4 < 4; c4++) {
                dr += acc[c4][i] * pr[c4];
                dt += acc[c4][i] * pt[c4];
            }
            dr += __shfl_xor(dr, 1); dt += __shfl_xor(dt, 1);
            dr += __shfl_xor(dr, 2); dt += __shfl_xor(dt, 2);
            dr += __shfl_xor(dr, 4); dt += __shfl_xor(dt, 4);
            dr += __shfl_xor(dr, 8); dt += __shfl_xor(dt, 8);
            if (n16 == 0) {
                atomicAdd(&sdr[g * 16 + quad * 4 + i], dr);
                atomicAdd(&sdt[g * 16 + quad * 4 + i], dt);
            }
        }
    }
    __syncthreads();
    if (threadIdx.x < 128) {
        int gr = blockIdx.x >> 4, e16 = blockIdx.x & 15;
        g_xc16[((sec * NB + gr) * 16 + e16) * 128 + threadIdx.x] = s[threadIdx.x];
    }
    if (DOTS && threadIdx.x < 32) {
        g_trel[rowbase + threadIdx.x] = sdr[threadIdx.x];
        g_troot[rowbase + threadIdx.x] = sdt[threadIdx.x];
    }
}

// ---------------- SAGPool: fused score + per-graph bitonic top-410 ----------
__global__ __launch_bounds__(256) void k_topk(const float* __restrict__ pb) {
    __shared__ float sv[512];
    __shared__ int si[512];
    int g = blockIdx.x, t = threadIdx.x;
    if (t == 0) { g_bcnt[g] = 0; g_bcur[g] = 0; }
    float pbv = pb[0];
    for (int l = t; l < 512; l += 256) {
        int node = g * 512 + l;
        int r0 = g_rows1[node], r1 = g_rows1[node + 1];
        float s = 0.f;
        int e = r0;
        for (; e + 4 <= r1; e += 4) {
            float s0 = g_trel[g_csr1u[e]];
            float s1 = g_trel[g_csr1u[e + 1]];
            float s2 = g_trel[g_csr1u[e + 2]];
            float s3 = g_trel[g_csr1u[e + 3]];
            s += (s0 + s1) + (s2 + s3);
        }
        for (; e < r1; e++) s += g_trel[g_csr1u[e]];
        sv[l] = s + g_troot[node] + pbv;
        si[l] = l;
    }
    __syncthreads();
    for (int k = 2; k <= 512; k <<= 1) {
        for (int j = k >> 1; j > 0; j >>= 1) {
            for (int i = t; i < 512; i += 256) {
                int p = i ^ j;
                if (p > i) {
                    float va = sv[i], vb = sv[p];
                    int ia = si[i], ib = si[p];
                    bool aFirst = (va > vb) || (va == vb && ia < ib);
                    bool up = ((i & k) == 0);
                    if (up != aFirst) { sv[i] = vb; sv[p] = va; si[i] = ib; si[p] = ia; }
                }
            }
            __syncthreads();
        }
    }
    for (int r = t; r < 512; r += 256) {
        int old = g * 512 + si[r];
        if (r < KK) {
            g_gatef[old] = tanhf(sv[r]);
            g_keptu[old] = 1;
        } else {
            g_gatef[old] = 0.f;
            g_keptu[old] = 0;
        }
    }
}

// ---------------- MLP head + log_softmax ------------------------------------
__global__ __launch_bounds__(128) void k_head(const float* __restrict__ W1, const float* __restrict__ b1,
                                              const float* __restrict__ W2, const float* __restrict__ b2,
                                              float* __restrict__ out) {
    __shared__ float xr[512];
    __shared__ float r0[128], r1[128];
    int g = blockIdx.x, t = threadIdx.x;
    for (int i = t; i < 512; i += 128) {
        int sec = i >> 7, c = i & 127;
        const float* p = &g_xc16[((sec * NB + g) * 16) * 128 + c];
        int nq = (sec == 0) ? 8 : 16;     // conv1 writes 8 partial slots
        float v = 0.f;
        for (int q = 0; q < nq; q++) v += p[q * 128];
        float inv = (sec < 2) ? (1.0f / 512.0f) : (1.0f / 410.0f);
        xr[i] = v * inv;
    }
    __syncthreads();
    float acc = b1[t];
    for (int k = 0; k < 512; k++) acc += xr[k] * W1[k * 128 + t];
    acc = fmaxf(acc, 0.f);
    r0[t] = acc * W2[t * 2 + 0];
    r1[t] = acc * W2[t * 2 + 1];
    __syncthreads();
    for (int off = 64; off > 0; off >>= 1) {
        if (t < off) { r0[t] += r0[t + off]; r1[t] += r1[t + off]; }
        __syncthreads();
    }
    if (t == 0) {
        float z0 = r0[0] + b2[0], z1 = r1[0] + b2[1];
        float m = fmaxf(z0, z1);
        float l = m + logf(expf(z0 - m) + expf(z1 - m));
        out[g * 2 + 0] = z0 - l;
        out[g * 2 + 1] = z1 - l;
    }
}

// ---------------- launch -----------------------------------------------------
extern "C" void kernel_launch(void* const* d_in, const int* in_sizes, int n_in,
                              void* d_out, int out_size, void* d_ws, size_t ws_size,
                              hipStream_t stream) {
    const float* x = (const float*)d_in[0];
    const int* ei = (const int*)d_in[1];
    const int* src = ei;
    const int* dst = ei + EE;
    const float* W1r = (const float*)d_in[3];
    const float* W1o = (const float*)d_in[4];
    const float* b1 = (const float*)d_in[5];
    const float* Wcr = (const float*)d_in[6];
    const float* Wco = (const float*)d_in[7];
    const float* bc = (const float*)d_in[8];
    const float* pwr = (const float*)d_in[9];
    const float* pwt = (const float*)d_in[10];
    const float* pb = (const float*)d_in[11];
    const float* l1W = (const float*)d_in[12];
    const float* l1b = (const float*)d_in[13];
    const float* l2W = (const float*)d_in[14];
    const float* l2b = (const float*)d_in[15];
    float* out = (float*)d_out;

    // ---- prep (x/weights -> bf16) + bucket histogram (independent halves) ----
    k_prep<<<5568, 256, 0, stream>>>(x, W1r, W1o, Wcr, Wco, dst);

    // ---- CSR1: scatter (local bucket scan), per-graph CSR (local scan) ----
    k_bscatter<<<1024, 256, 0, stream>>>(src, dst);
    k_bcsr<<<128, 512, 0, stream>>>();

    // ---- conv1: hb1 = relu([agg64(xb)|xb]@wt1+b1); pool sec0 ----
    k_conv1<<<1024, 256, 0, stream>>>(b1);

    // ---- conv2 -> hb2; pool sec1; score dots fused ----
    k_conv<0, 0, 0, 1, 0><<<2048, 256, 0, stream>>>(1, 1, 0, bc, 2, 1, pwr, pwt);

    // ---- SAGPool: fused score + top-410 -> gatef/keptu (+ counter re-zero) ----
    k_topk<<<NB, 256, 0, stream>>>(pb);

    // ---- conv3: gated agg(hb2), kept-denom, BGATE root, masked -> hb1; sec2 ----
    k_conv<1, 1, 1, 0, 1><<<2048, 256, 0, stream>>>(2, 2, 32768, bc + 128, 1, 2, pwr, pwt);

    // ---- conv4: agg(hb1), kinv reuse, masked -> hb2; sec3 ----
    k_conv<2, 0, 1, 0, 0><<<2048, 256, 0, stream>>>(1, 1, 65536, bc + 256, 2, 3, pwr, pwt);

    // ---- head ----
    k_head<<<NB, 128, 0, stream>>>(l1W, l1b, l2W, l2b, out);
}

// Round 13
// 511.073 us; speedup vs baseline: 1.0953x; 1.0315x over previous
//
#include <hip/hip_runtime.h>
#include <math.h>

#define NT 65536
#define EE 1048576
#define NB 128
#define KK 410          // kept nodes per graph = ceil(0.8*512)
#define HH 128

typedef short bf16x8 __attribute__((ext_vector_type(8)));
typedef float f32x4 __attribute__((ext_vector_type(4)));

// ---------------- device scratch -------------------------------------------
__device__ unsigned short g_xb[(size_t)NT * 64];
__device__ unsigned short g_hb1[(size_t)NT * HH];
__device__ unsigned short g_hb2[(size_t)NT * HH];
__device__ unsigned short g_wt1[128 * 128];
__device__ unsigned short g_wtc[3 * 128 * 256];
__device__ unsigned short g_csr1u[EE];   // src per edge, grouped by (dst, src-octant)
__device__ unsigned short g_keptu[NT];   // 1 if node kept by SAGPool
__device__ unsigned int g_ebuck[EE];     // packed (dstLocal<<16)|src, bucketed by graph
__device__ int g_bcnt[128];              // zero at load; re-zeroed by k_topk each call
__device__ int g_bcur[128];              // ditto
__device__ float g_trel[NT];
__device__ float g_troot[NT];
__device__ float g_gatef[NT];            // tanh(score) if kept else 0
__device__ float g_kinv[NT];             // 1/max(kept-neighbor count,1)
__device__ float g_xc32[4 * NB * 32 * 128]; // pooled partials [sec][graph][slot][128]
__device__ int g_rows1[NT + 1];

__device__ __forceinline__ float b2f(unsigned short u) {
    union { unsigned int i; float f; } v;
    v.i = ((unsigned int)u) << 16;
    return v.f;
}
__device__ __forceinline__ unsigned short f2b(float f) {
    unsigned int x = __float_as_uint(f);
    unsigned int r = x + 0x7fffu + ((x >> 16) & 1u);   // round-to-nearest-even
    return (unsigned short)(r >> 16);
}
__device__ __forceinline__ bf16x8 scale8(bf16x8 a, float g) {
    bf16x8 r;
#pragma unroll
    for (int i = 0; i < 8; i++) {
        unsigned short u = (unsigned short)a[i];
        r[i] = (short)f2b(b2f(u) * g);
    }
    return r;
}

// ---------------- prep + bucket histogram (independent halves, no handoff) --
// NOTE (R7 post-mortem): never do grid-wide producer->consumer handoff inside
// one kernel via __threadfence on CDNA4 — per-XCD L2 non-coherence makes each
// block's device-scope fence an L2 writeback (5568 of them = 450us).
__global__ __launch_bounds__(256) void k_prep(const float* __restrict__ x,
                                              const float* __restrict__ W1r,
                                              const float* __restrict__ W1o,
                                              const float* __restrict__ Wcr,
                                              const float* __restrict__ Wco,
                                              const int* __restrict__ dst) {
    if (blockIdx.x < 4544) {
        int tid = blockIdx.x * 256 + threadIdx.x;
        if (tid < 1048576) {
            float4 v = *(const float4*)&x[(size_t)tid * 4];
            unsigned int lo = (unsigned int)f2b(v.x) | ((unsigned int)f2b(v.y) << 16);
            unsigned int hi = (unsigned int)f2b(v.z) | ((unsigned int)f2b(v.w) << 16);
            *(uint2*)&g_xb[(size_t)tid * 4] = make_uint2(lo, hi);
        } else if (tid < 1048576 + 16384) {
            int r = tid - 1048576;
            int k = r & 127, n = r >> 7;
            float v = (k < 64) ? W1r[k * 128 + n] : W1o[(k - 64) * 128 + n];
            g_wt1[n * 128 + k] = f2b(v);
        } else {
            int r = tid - (1048576 + 16384);
            int l = r >> 15;
            int k = r & 255, n = (r >> 8) & 127;
            float v = (k < 128) ? Wcr[l * 16384 + k * 128 + n]
                                : Wco[l * 16384 + (k - 128) * 128 + n];
            g_wtc[l * 32768 + n * 256 + k] = f2b(v);
        }
    } else {
        __shared__ int h[128];
        if (threadIdx.x < 128) h[threadIdx.x] = 0;
        __syncthreads();
        int e0 = ((blockIdx.x - 4544) * 256 + threadIdx.x) * 4;
        int4 d = *(const int4*)&dst[e0];
        atomicAdd(&h[d.x >> 9], 1);
        atomicAdd(&h[d.y >> 9], 1);
        atomicAdd(&h[d.z >> 9], 1);
        atomicAdd(&h[d.w >> 9], 1);
        __syncthreads();
        if (threadIdx.x < 128 && h[threadIdx.x]) atomicAdd(&g_bcnt[threadIdx.x], h[threadIdx.x]);
    }
}

// ---------------- CSR1: scatter into bucket regions (local bucket scan) -----
__global__ __launch_bounds__(256) void k_bscatter(const int* __restrict__ src,
                                                  const int* __restrict__ dst) {
    __shared__ int h[128];
    __shared__ int base[128];
    __shared__ int sc[128];
    __shared__ int vv[128];
    int t = threadIdx.x;
    if (t < 128) { vv[t] = g_bcnt[t]; sc[t] = vv[t]; h[t] = 0; }
    __syncthreads();
    for (int off = 1; off < 128; off <<= 1) {
        int u = (t >= off && t < 128) ? sc[t - off] : 0;
        __syncthreads();
        if (t < 128) sc[t] += u;
        __syncthreads();
    }
    int e0 = (blockIdx.x * 256 + t) * 4;
    int4 s = *(const int4*)&src[e0];
    int4 d = *(const int4*)&dst[e0];
    int b0 = d.x >> 9, b1 = d.y >> 9, b2 = d.z >> 9, b3 = d.w >> 9;
    atomicAdd(&h[b0], 1);
    atomicAdd(&h[b1], 1);
    atomicAdd(&h[b2], 1);
    atomicAdd(&h[b3], 1);
    __syncthreads();
    if (t < 128) {
        int c = h[t];
        base[t] = (sc[t] - vv[t]) + (c ? atomicAdd(&g_bcur[t], c) : 0);
        h[t] = 0;
    }
    __syncthreads();
    int r0 = atomicAdd(&h[b0], 1);
    g_ebuck[base[b0] + r0] = ((unsigned int)(d.x & 511) << 16) | (unsigned int)s.x;
    int r1 = atomicAdd(&h[b1], 1);
    g_ebuck[base[b1] + r1] = ((unsigned int)(d.y & 511) << 16) | (unsigned int)s.y;
    int r2 = atomicAdd(&h[b2], 1);
    g_ebuck[base[b2] + r2] = ((unsigned int)(d.z & 511) << 16) | (unsigned int)s.z;
    int r3 = atomicAdd(&h[b3], 1);
    g_ebuck[base[b3] + r3] = ((unsigned int)(d.w & 511) << 16) | (unsigned int)s.w;
}

// ---------------- CSR1: per-graph CSR, edges octant-sorted by src -----------
// Key = (dstLocal<<3) | (src>>13): within each row, edges are grouped by src
// octant (8KB x ... = 2MB slice of the 16MB h table). All lanes walk their
// lists in the same octant order -> machine-wide temporal locality -> per-XCD
// L2 (4MB) holds the active slice -> L2 hit rate up, gather latency down.
__global__ __launch_bounds__(512) void k_bcsr() {
    __shared__ int hist[4096];
    __shared__ int cur[4096];
    __shared__ int sc[128];
    __shared__ int temp[512];
    int g = blockIdx.x, t = threadIdx.x;
    if (t < 128) sc[t] = g_bcnt[t];
    for (int i = t; i < 4096; i += 512) { hist[i] = 0; cur[i] = 0; }
    __syncthreads();
    for (int off = 1; off < 128; off <<= 1) {
        int u = (t >= off && t < 128) ? sc[t - off] : 0;
        __syncthreads();
        if (t < 128) sc[t] += u;
        __syncthreads();
    }
    int b0 = sc[g] - g_bcnt[g];          // exclusive prefix
    int b1 = sc[g];
    __syncthreads();
    for (int e = b0 + t; e < b1; e += 512) {
        unsigned int p = g_ebuck[e];
        int key = (int)((p >> 16) << 3) | (int)((p & 0xFFFFu) >> 13);
        atomicAdd(&hist[key], 1);
    }
    __syncthreads();
    // exclusive scan of hist[4096]: thread t owns bins [t*8, t*8+8) = row t's octants
    int vals[8];
    int s8 = 0;
#pragma unroll
    for (int j = 0; j < 8; j++) { vals[j] = hist[t * 8 + j]; s8 += vals[j]; }
    temp[t] = s8;
    __syncthreads();
    for (int off = 1; off < 512; off <<= 1) {
        int u = (t >= off) ? temp[t - off] : 0;
        __syncthreads();
        temp[t] += u;
        __syncthreads();
    }
    int excl = temp[t] - s8;
    int run = excl;
#pragma unroll
    for (int j = 0; j < 8; j++) { int v = vals[j]; hist[t * 8 + j] = run; run += v; }
    g_rows1[g * 512 + t] = b0 + excl;
    if (t == 511) g_rows1[g * 512 + 512] = b0 + excl + s8;
    __syncthreads();
    for (int e = b0 + t; e < b1; e += 512) {
        unsigned int p = g_ebuck[e];
        unsigned int srcv = p & 0xFFFFu;
        int key = (int)((p >> 16) << 3) | (int)(srcv >> 13);
        int r = atomicAdd(&cur[key], 1);
        g_csr1u[b0 + hist[key] + r] = (unsigned short)srcv;
    }
}

// ---------------- conv1: register-fragment (K=64|64), 64 rows/block ---------
__global__ __launch_bounds__(256, 4) void k_conv1(const float* __restrict__ bias) {
    const unsigned short* h = g_xb;
    const unsigned short* Wt = g_wt1;
    unsigned short* out = g_hb1;
    __shared__ float s[128];
    int lane = threadIdx.x & 63;
    int w = threadIdx.x >> 6;
    int n16 = lane & 15, quad = lane >> 4;
    int rowbase = blockIdx.x * 64;
    int rowg = rowbase + w * 16;
    int node = rowg + n16;
    if (threadIdx.x < 128) s[threadIdx.x] = 0.f;
    int r0 = g_rows1[node], r1 = g_rows1[node + 1];
    float aggacc[2][8];
#pragma unroll
    for (int ch = 0; ch < 2; ch++)
#pragma unroll
        for (int j = 0; j < 8; j++) aggacc[ch][j] = 0.f;
    const unsigned short* hq = h + quad * 8;
#define ACC8(arow, v)                                            \
    arow[0] += b2f((unsigned short)(v.x & 0xffff));              \
    arow[1] += b2f((unsigned short)(v.x >> 16));                 \
    arow[2] += b2f((unsigned short)(v.y & 0xffff));              \
    arow[3] += b2f((unsigned short)(v.y >> 16));                 \
    arow[4] += b2f((unsigned short)(v.z & 0xffff));              \
    arow[5] += b2f((unsigned short)(v.z >> 16));                 \
    arow[6] += b2f((unsigned short)(v.w & 0xffff));              \
    arow[7] += b2f((unsigned short)(v.w >> 16));
    int e = r0;
    for (; e + 2 <= r1; e += 2) {
        int i0 = g_csr1u[e], i1 = g_csr1u[e + 1];
        uint4 v00 = *(const uint4*)&hq[(size_t)i0 * 64];
        uint4 v01 = *(const uint4*)&hq[(size_t)i0 * 64 + 32];
        uint4 v10 = *(const uint4*)&hq[(size_t)i1 * 64];
        uint4 v11 = *(const uint4*)&hq[(size_t)i1 * 64 + 32];
        ACC8(aggacc[0], v00) ACC8(aggacc[1], v01)
        ACC8(aggacc[0], v10) ACC8(aggacc[1], v11)
    }
    if (e < r1) {
        int i0 = g_csr1u[e];
        uint4 v00 = *(const uint4*)&hq[(size_t)i0 * 64];
        uint4 v01 = *(const uint4*)&hq[(size_t)i0 * 64 + 32];
        ACC8(aggacc[0], v00) ACC8(aggacc[1], v01)
    }
#undef ACC8
    int c = r1 - r0;
    float inv = 1.0f / (float)(c > 0 ? c : 1);
    bf16x8 afrag[2];
#pragma unroll
    for (int ch = 0; ch < 2; ch++)
#pragma unroll
        for (int j = 0; j < 8; j++) afrag[ch][j] = (short)f2b(aggacc[ch][j] * inv);

    f32x4 acc[8];
#pragma unroll
    for (int ct = 0; ct < 8; ct++)
#pragma unroll
        for (int i = 0; i < 4; i++) acc[ct][i] = 0.f;
#pragma unroll
    for (int ks = 0; ks < 4; ks++) {
        bf16x8 a;
        if (ks < 2) a = afrag[ks];
        else a = *(const bf16x8*)&g_xb[(size_t)node * 64 + (ks - 2) * 32 + quad * 8];
#pragma unroll
        for (int ct = 0; ct < 8; ct++) {
            bf16x8 b = *(const bf16x8*)&Wt[(size_t)(ct * 16 + n16) * 128 + ks * 32 + quad * 8];
            acc[ct] = __builtin_amdgcn_mfma_f32_16x16x32_bf16(a, b, acc[ct], 0, 0, 0);
        }
    }
#pragma unroll
    for (int ct = 0; ct < 8; ct++) {
        int cc = ct * 16 + n16;
        float bv = bias[cc];
#pragma unroll
        for (int i = 0; i < 4; i++) {
            int r = rowg + quad * 4 + i;
            float v = fmaxf(acc[ct][i] + bv, 0.f);
            acc[ct][i] = v;
            out[(size_t)r * 128 + cc] = f2b(v);
        }
    }
    __syncthreads();
#pragma unroll
    for (int ct = 0; ct < 8; ct++) {
        float p = acc[ct][0] + acc[ct][1] + acc[ct][2] + acc[ct][3];
        p += __shfl_xor(p, 16);
        p += __shfl_xor(p, 32);
        if (quad == 0) atomicAdd(&s[ct * 16 + n16], p);
    }
    __syncthreads();
    if (threadIdx.x < 128) {
        int gr = blockIdx.x >> 3, e8 = blockIdx.x & 7;   // 8 partial slots (sec 0)
        g_xc32[((0 * NB + gr) * 32 + e8) * 128 + threadIdx.x] = s[threadIdx.x];
    }
}

// ---------------- fused conv, R4-shape gather (K=128|128) -------------------
// Block 256 = 4 waves = ONE 16-row MFMA tile; grid NT/16 = 4096 (32 waves/CU).
// Gather phase = R4's proven 3.5TB/s shape: wave = 4 rows x 16 lanes, each
// lane 16B per edge (full 256B row per 16-lane group), unroll-4, ~40 VGPR.
// One barrier; all 4 waves MFMA the shared tile splitting 8 col-tiles 2 each
// (acc = 8 VGPR).
// KC: 0 denom=deg; 1 denom=kept count + store g_kinv; 2 read g_kinv
template <int KC, int GATED, int MASKED, int DOTS, int BGATE>
__global__ __launch_bounds__(256, 8) void k_conv(int hSel, int bSel, int wOfs,
                                                 const float* __restrict__ bias, int outSel,
                                                 int sec,
                                                 const float* __restrict__ pwr,
                                                 const float* __restrict__ pwt) {
    const unsigned short* h = hSel == 1 ? g_hb1 : g_hb2;
    const unsigned short* Bp = bSel == 1 ? g_hb1 : g_hb2;
    const unsigned short* Wt = g_wtc + wOfs;
    unsigned short* out = outSel == 1 ? g_hb1 : g_hb2;
    __shared__ unsigned short frag[16][136];      // bf16 A-frags (+pad)
    __shared__ float s[128];
    __shared__ float sdr[16], sdt[16];
    int lane = threadIdx.x & 63;
    int w = threadIdx.x >> 6;              // 0..3
    int rowbase = blockIdx.x * 16;
    if (threadIdx.x < 128) s[threadIdx.x] = 0.f;
    if (threadIdx.x < 16) { sdr[threadIdx.x] = 0.f; sdt[threadIdx.x] = 0.f; }

    // ---------- phase 1: gather-aggregate (R4 shape) ----------
    {
        int rl = lane >> 4;                // 0..3 (row within wave)
        int c16 = lane & 15;               // 16B col slice
        int m = w * 4 + rl;                // row within tile (MFMA m index)
        int row = rowbase + m;
        int r0 = g_rows1[row], r1 = g_rows1[row + 1];
        float kinv_pre = (KC == 2) ? g_kinv[row] : 0.f;
        float acc8[8];
#pragma unroll
        for (int j = 0; j < 8; j++) acc8[j] = 0.f;
        int kc = 0;
        const unsigned short* hq = h + c16 * 8;
#define ACC8(v, gf)                                              \
    acc8[0] += gf * b2f((unsigned short)(v.x & 0xffff));         \
    acc8[1] += gf * b2f((unsigned short)(v.x >> 16));            \
    acc8[2] += gf * b2f((unsigned short)(v.y & 0xffff));         \
    acc8[3] += gf * b2f((unsigned short)(v.y >> 16));            \
    acc8[4] += gf * b2f((unsigned short)(v.z & 0xffff));         \
    acc8[5] += gf * b2f((unsigned short)(v.z >> 16));            \
    acc8[6] += gf * b2f((unsigned short)(v.w & 0xffff));         \
    acc8[7] += gf * b2f((unsigned short)(v.w >> 16));
        int e = r0;
        for (; e + 4 <= r1; e += 4) {
            int i0 = g_csr1u[e], i1 = g_csr1u[e + 1];
            int i2 = g_csr1u[e + 2], i3 = g_csr1u[e + 3];
            uint4 v0 = *(const uint4*)&hq[(size_t)i0 * 128];
            uint4 v1 = *(const uint4*)&hq[(size_t)i1 * 128];
            uint4 v2 = *(const uint4*)&hq[(size_t)i2 * 128];
            uint4 v3 = *(const uint4*)&hq[(size_t)i3 * 128];
            float g0 = GATED ? g_gatef[i0] : 1.0f;
            float g1 = GATED ? g_gatef[i1] : 1.0f;
            float g2 = GATED ? g_gatef[i2] : 1.0f;
            float g3 = GATED ? g_gatef[i3] : 1.0f;
            if (KC == 1)
                kc += (int)g_keptu[i0] + (int)g_keptu[i1]
                    + (int)g_keptu[i2] + (int)g_keptu[i3];
            ACC8(v0, g0) ACC8(v1, g1) ACC8(v2, g2) ACC8(v3, g3)
        }
        for (; e < r1; e++) {
            int i0 = g_csr1u[e];
            uint4 v0 = *(const uint4*)&hq[(size_t)i0 * 128];
            float g0 = GATED ? g_gatef[i0] : 1.0f;
            if (KC == 1) kc += (int)g_keptu[i0];
            ACC8(v0, g0)
        }
#undef ACC8
        float inv;
        if (KC == 0) {
            int c = r1 - r0;
            inv = 1.0f / (float)(c > 0 ? c : 1);
        } else if (KC == 1) {
            inv = 1.0f / (float)(kc > 0 ? kc : 1);
            if (c16 == 0) g_kinv[row] = inv;
        } else {
            inv = kinv_pre;
        }
        bf16x8 fk;
#pragma unroll
        for (int j = 0; j < 8; j++) fk[j] = (short)f2b(acc8[j] * inv);
        *(bf16x8*)&frag[m][c16 * 8] = fk;
    }
    __syncthreads();

    // ---------- phase 2: MFMA, 4 waves split 8 col-tiles 2 each ----------
    int n16 = lane & 15, quad = lane >> 4;
    int node = rowbase + n16;
    float ga = BGATE ? g_gatef[node] : 1.0f;
    f32x4 acc[2];
#pragma unroll
    for (int c2 = 0; c2 < 2; c2++)
#pragma unroll
        for (int i = 0; i < 4; i++) acc[c2][i] = 0.f;
#pragma unroll
    for (int ks = 0; ks < 8; ks++) {
        bf16x8 a;
        if (ks < 4) {
            a = *(const bf16x8*)&frag[n16][ks * 32 + quad * 8];
        } else {
            a = *(const bf16x8*)&Bp[(size_t)node * 128 + (ks - 4) * 32 + quad * 8];
            if (BGATE) a = scale8(a, ga);
        }
#pragma unroll
        for (int c2 = 0; c2 < 2; c2++) {
            int ct = w * 2 + c2;
            bf16x8 b = *(const bf16x8*)&Wt[(size_t)(ct * 16 + n16) * 256 + ks * 32 + quad * 8];
            acc[c2] = __builtin_amdgcn_mfma_f32_16x16x32_bf16(a, b, acc[c2], 0, 0, 0);
        }
    }

    // ---------- epilogue (C/D: col=ct*16+n16, row=quad*4+i) ----------
    {
        float m[4];
#pragma unroll
        for (int i = 0; i < 4; i++) {
            int r = rowbase + quad * 4 + i;
            m[i] = (!MASKED || g_keptu[r]) ? 1.0f : 0.0f;
        }
#pragma unroll
        for (int c2 = 0; c2 < 2; c2++) {
            int c = (w * 2 + c2) * 16 + n16;
            float bv = bias[c];
#pragma unroll
            for (int i = 0; i < 4; i++) {
                int r = rowbase + quad * 4 + i;
                float v = fmaxf(acc[c2][i] + bv, 0.f) * m[i];
                acc[c2][i] = v;
                out[(size_t)r * 128 + c] = f2b(v);
            }
        }
    }

    // pool partials: column sums over this tile's 16 rows
#pragma unroll
    for (int c2 = 0; c2 < 2; c2++) {
        float p = acc[c2][0] + acc[c2][1] + acc[c2][2] + acc[c2][3];
        p += __shfl_xor(p, 16);
        p += __shfl_xor(p, 32);
        if (quad == 0) atomicAdd(&s[(w * 2 + c2) * 16 + n16], p);
    }

    // DOTS partials (conv2): each wave contributes its 2 col-tiles to row dots
    if (DOTS) {
        float pr[2], pt[2];
#pragma unroll
        for (int c2 = 0; c2 < 2; c2++) {
            pr[c2] = pwr[(w * 2 + c2) * 16 + n16];
            pt[c2] = pwt[(w * 2 + c2) * 16 + n16];
        }
#pragma unroll
        for (int i = 0; i < 4; i++) {
            float dr = acc[0][i] * pr[0] + acc[1][i] * pr[1];
            float dt = acc[0][i] * pt[0] + acc[1][i] * pt[1];
            dr += __shfl_xor(dr, 1); dt += __shfl_xor(dt, 1);
            dr += __shfl_xor(dr, 2); dt += __shfl_xor(dt, 2);
            dr += __shfl_xor(dr, 4); dt += __shfl_xor(dt, 4);
            dr += __shfl_xor(dr, 8); dt += __shfl_xor(dt, 8);
            if (n16 == 0) {
                atomicAdd(&sdr[quad * 4 + i], dr);
                atomicAdd(&sdt[quad * 4 + i], dt);
            }
        }
    }
    __syncthreads();
    if (threadIdx.x < 128) {
        int gr = blockIdx.x >> 5, slot = blockIdx.x & 31;
        g_xc32[((sec * NB + gr) * 32 + slot) * 128 + threadIdx.x] = s[threadIdx.x];
    }
    if (DOTS && threadIdx.x < 16) {
        g_trel[rowbase + threadIdx.x] = sdr[threadIdx.x];
        g_troot[rowbase + threadIdx.x] = sdt[threadIdx.x];
    }
}

// ---------------- SAGPool: fused score + per-graph bitonic top-410 ----------
__global__ __launch_bounds__(256) void k_topk(const float* __restrict__ pb) {
    __shared__ float sv[512];
    __shared__ int si[512];
    int g = blockIdx.x, t = threadIdx.x;
    if (t == 0) { g_bcnt[g] = 0; g_bcur[g] = 0; }
    float pbv = pb[0];
    for (int l = t; l < 512; l += 256) {
        int node = g * 512 + l;
        int r0 = g_rows1[node], r1 = g_rows1[node + 1];
        float s = 0.f;
        int e = r0;
        for (; e + 4 <= r1; e += 4) {
            float s0 = g_trel[g_csr1u[e]];
            float s1 = g_trel[g_csr1u[e + 1]];
            float s2 = g_trel[g_csr1u[e + 2]];
            float s3 = g_trel[g_csr1u[e + 3]];
            s += (s0 + s1) + (s2 + s3);
        }
        for (; e < r1; e++) s += g_trel[g_csr1u[e]];
        sv[l] = s + g_troot[node] + pbv;
        si[l] = l;
    }
    __syncthreads();
    for (int k = 2; k <= 512; k <<= 1) {
        for (int j = k >> 1; j > 0; j >>= 1) {
            for (int i = t; i < 512; i += 256) {
                int p = i ^ j;
                if (p > i) {
                    float va = sv[i], vb = sv[p];
                    int ia = si[i], ib = si[p];
                    bool aFirst = (va > vb) || (va == vb && ia < ib);
                    bool up = ((i & k) == 0);
                    if (up != aFirst) { sv[i] = vb; sv[p] = va; si[i] = ib; si[p] = ia; }
                }
            }
            __syncthreads();
        }
    }
    for (int r = t; r < 512; r += 256) {
        int old = g * 512 + si[r];
        if (r < KK) {
            g_gatef[old] = tanhf(sv[r]);
            g_keptu[old] = 1;
        } else {
            g_gatef[old] = 0.f;
            g_keptu[old] = 0;
        }
    }
}

// ---------------- MLP head + log_softmax ------------------------------------
__global__ __launch_bounds__(128) void k_head(const float* __restrict__ W1, const float* __restrict__ b1,
                                              const float* __restrict__ W2, const float* __restrict__ b2,
                                              float* __restrict__ out) {
    __shared__ float xr[512];
    __shared__ float r0[128], r1[128];
    int g = blockIdx.x, t = threadIdx.x;
    for (int i = t; i < 512; i += 128) {
        int sec = i >> 7, c = i & 127;
        const float* p = &g_xc32[((sec * NB + g) * 32) * 128 + c];
        int nq = (sec == 0) ? 8 : 32;     // conv1 writes 8 partial slots
        float v = 0.f;
        for (int q = 0; q < nq; q++) v += p[q * 128];
        float inv = (sec < 2) ? (1.0f / 512.0f) : (1.0f / 410.0f);
        xr[i] = v * inv;
    }
    __syncthreads();
    float acc = b1[t];
    for (int k = 0; k < 512; k++) acc += xr[k] * W1[k * 128 + t];
    acc = fmaxf(acc, 0.f);
    r0[t] = acc * W2[t * 2 + 0];
    r1[t] = acc * W2[t * 2 + 1];
    __syncthreads();
    for (int off = 64; off > 0; off >>= 1) {
        if (t < off) { r0[t] += r0[t + off]; r1[t] += r1[t + off]; }
        __syncthreads();
    }
    if (t == 0) {
        float z0 = r0[0] + b2[0], z1 = r1[0] + b2[1];
        float m = fmaxf(z0, z1);
        float l = m + logf(expf(z0 - m) + expf(z1 - m));
        out[g * 2 + 0] = z0 - l;
        out[g * 2 + 1] = z1 - l;
    }
}

// ---------------- launch -----------------------------------------------------
extern "C" void kernel_launch(void* const* d_in, const int* in_sizes, int n_in,
                              void* d_out, int out_size, void* d_ws, size_t ws_size,
                              hipStream_t stream) {
    const float* x = (const float*)d_in[0];
    const int* ei = (const int*)d_in[1];
    const int* src = ei;
    const int* dst = ei + EE;
    const float* W1r = (const float*)d_in[3];
    const float* W1o = (const float*)d_in[4];
    const float* b1 = (const float*)d_in[5];
    const float* Wcr = (const float*)d_in[6];
    const float* Wco = (const float*)d_in[7];
    const float* bc = (const float*)d_in[8];
    const float* pwr = (const float*)d_in[9];
    const float* pwt = (const float*)d_in[10];
    const float* pb = (const float*)d_in[11];
    const float* l1W = (const float*)d_in[12];
    const float* l1b = (const float*)d_in[13];
    const float* l2W = (const float*)d_in[14];
    const float* l2b = (const float*)d_in[15];
    float* out = (float*)d_out;

    // ---- prep (x/weights -> bf16) + bucket histogram (independent halves) ----
    k_prep<<<5568, 256, 0, stream>>>(x, W1r, W1o, Wcr, Wco, dst);

    // ---- CSR1: scatter (local bucket scan), per-graph octant-sorted CSR ----
    k_bscatter<<<1024, 256, 0, stream>>>(src, dst);
    k_bcsr<<<128, 512, 0, stream>>>();

    // ---- conv1: hb1 = relu([agg64(xb)|xb]@wt1+b1); pool sec0 ----
    k_conv1<<<1024, 256, 0, stream>>>(b1);

    // ---- conv2 -> hb2; pool sec1; score dots fused ----
    k_conv<0, 0, 0, 1, 0><<<4096, 256, 0, stream>>>(1, 1, 0, bc, 2, 1, pwr, pwt);

    // ---- SAGPool: fused score + top-410 -> gatef/keptu (+ counter re-zero) ----
    k_topk<<<NB, 256, 0, stream>>>(pb);

    // ---- conv3: gated agg(hb2), kept-denom, BGATE root, masked -> hb1; sec2 ----
    k_conv<1, 1, 1, 0, 1><<<4096, 256, 0, stream>>>(2, 2, 32768, bc + 128, 1, 2, pwr, pwt);

    // ---- conv4: agg(hb1), kinv reuse, masked -> hb2; sec3 ----
    k_conv<2, 0, 1, 0, 0><<<4096, 256, 0, stream>>>(1, 1, 65536, bc + 256, 2, 3, pwr, pwt);

    // ---- head ----
    k_head<<<NB, 128, 0, stream>>>(l1W, l1b, l2W, l2b, out);
}